// Round 22
// baseline (110.272 us; speedup 1.0000x reference)
//
#include <hip/hip_runtime.h>

// Problem constants: B=2, S=2048, D=1024, H=16, HD=64
#define B_  2
#define S_  2048
#define D_  1024
#define H_  16
#define HD_ 64
#define TD_ 3072   // 3*D

typedef __bf16 bf16x8 __attribute__((ext_vector_type(8)));
typedef float  f32x4  __attribute__((ext_vector_type(4)));
typedef float  f32x16 __attribute__((ext_vector_type(16)));

#define AS1 __attribute__((address_space(1)))
#define AS3 __attribute__((address_space(3)))

#define MASKVAL (-60000.0f)
#define MINITVAL (-30000.0f)

__device__ __forceinline__ unsigned short f2bf(float f) {
  return __builtin_bit_cast(unsigned short, (__bf16)f);
}

__device__ __forceinline__ unsigned int pkbf(float lo, float hi) {
  unsigned int r;
  asm("v_cvt_pk_bf16_f32 %0, %1, %2" : "=v"(r) : "v"(lo), "v"(hi));
  return r;
}

// v_permlane32_swap_b32: a[32+i] <-> b[i]  (proven, distinct operands)
__device__ __forceinline__ void plswap(unsigned int& a, unsigned int& b) {
  asm volatile("v_permlane32_swap_b32 %0, %1" : "+v"(a), "+v"(b));
}

__device__ __forceinline__ float exp2a(float x) {
  return __builtin_amdgcn_exp2f(x);
}

__device__ __forceinline__ float xmax32(float x) {
  return fmaxf(x, __shfl_xor(x, 32, 64));
}
__device__ __forceinline__ float xadd32(float x) {
  return x + __shfl_xor(x, 32, 64);
}

__device__ __forceinline__ void gload16(const void* g, void* l) {
  __builtin_amdgcn_global_load_lds((const AS1 void*)g, (AS3 void*)l, 16, 0, 0);
}

// ---------------- fused prep: x->bf16  AND  both W transposes ------------
__global__ __launch_bounds__(256) void k_prep(const float* __restrict__ x,
                                              const float* __restrict__ wa,
                                              const float* __restrict__ wp,
                                              unsigned short* __restrict__ xb,
                                              unsigned short* __restrict__ waT,
                                              unsigned short* __restrict__ wpT) {
  __shared__ __align__(16) unsigned short tile[64][72];
  const int t = threadIdx.x;
  const int bid = blockIdx.x;
  if (bid < 4096) {
    const int i = (bid * 256 + t) * 4;
    float4 v = *(const float4*)(x + i);
    ushort4 o;
    o.x = f2bf(v.x); o.y = f2bf(v.y); o.z = f2bf(v.z); o.w = f2bf(v.w);
    *(ushort4*)(xb + i) = o;
    return;
  }
  const int idx = bid - 4096;               // 0..1023
  const int bx = idx & 63;                  // 0..63
  const int by = idx >> 6;                  // 0..15
  const float* w;
  unsigned short* wt;
  int C, c0;
  if (bx < 48) { w = wa; wt = waT; C = TD_; c0 = bx * 64; }
  else         { w = wp; wt = wpT; C = D_;  c0 = (bx - 48) * 64; }
  const int R = D_;
  const int r0 = by * 64;
  const int rr = t >> 2, cc = (t & 3) * 16;
  const float* src = w + (size_t)(r0 + rr) * C + c0 + cc;
#pragma unroll
  for (int j = 0; j < 16; j += 4) {
    float4 v = *(const float4*)(src + j);
    tile[rr][cc + j + 0] = f2bf(v.x);
    tile[rr][cc + j + 1] = f2bf(v.y);
    tile[rr][cc + j + 2] = f2bf(v.z);
    tile[rr][cc + j + 3] = f2bf(v.w);
  }
  __syncthreads();
  unsigned short* dst = wt + (size_t)(c0 + rr) * R + r0 + cc;
#pragma unroll
  for (int j = 0; j < 16; j += 2) {
    unsigned int pk = (unsigned int)tile[cc + j][rr] |
                      ((unsigned int)tile[cc + j + 1][rr] << 16);
    *(unsigned int*)(dst + j) = pk;
  }
}

// ---------------- GEMM qkv: 128x128 tile, 2-PHASE double-buffered --------
// 2x arithmetic intensity vs 64x128 (32 MFMA per 32KB staged); pipelined so
// staging hides under compute. LDS 64KB -> 2 blocks/CU. Epilogue = proven
// round-15 128-row maps: Q row-major, K/V packed fragment-major.
__global__ __launch_bounds__(256) void k_gemm_qkv(const unsigned short* __restrict__ A,
                                                  const unsigned short* __restrict__ Bt,
                                                  unsigned short* __restrict__ qb,
                                                  unsigned short* __restrict__ kp,
                                                  unsigned short* __restrict__ vp) {
  __shared__ __align__(16) unsigned short ldsA[2][128 * 64];
  __shared__ __align__(16) unsigned short ldsB[2][128 * 64];
  const int K = D_;
  const int t = threadIdx.x;
  const int lane = t & 63;
  const int wid = t >> 6;
  const int wr = wid >> 1, wc = wid & 1;   // wave: 64 rows x 64 cols
  const int bx = blockIdx.x;
  const int bm = blockIdx.y * 128;
  const int bn = (((bx & 7) * 3) + (bx >> 3)) * 128;   // bijective for 24
  const int r = lane & 15, g = lane >> 4;

  f32x4 acc[4][4] = {};

  auto stage = [&](int buf, int kt) {
#pragma unroll
    for (int c = 0; c < 4; ++c) {
      const int idx = c * 256 + t;
      const int row = idx >> 3;
      const int col = ((idx & 7) ^ (row & 7)) * 8;
      gload16(A + (size_t)(bm + row) * K + kt + col, &ldsA[buf][idx * 8]);
      gload16(Bt + (size_t)(bn + row) * K + kt + col, &ldsB[buf][idx * 8]);
    }
  };

  stage(0, 0);
  asm volatile("s_waitcnt vmcnt(0)" ::: "memory");
  __syncthreads();

  int cur = 0;
  for (int kt = 0; kt < K; kt += 64) {
    if (kt + 64 < K) stage(cur ^ 1, kt + 64);   // issue next tile's loads

    __builtin_amdgcn_s_setprio(1);
#pragma unroll
    for (int ks = 0; ks < 2; ++ks) {
      bf16x8 af[4], bfr[4];
#pragma unroll
      for (int m = 0; m < 4; ++m) {
        const int row = wr * 64 + m * 16 + r;
        const int slot = (ks * 4 + g) ^ (row & 7);
        af[m] = *(const bf16x8*)(&ldsA[cur][row * 64 + slot * 8]);
      }
#pragma unroll
      for (int n = 0; n < 4; ++n) {
        const int row = wc * 64 + n * 16 + r;
        const int slot = (ks * 4 + g) ^ (row & 7);
        bfr[n] = *(const bf16x8*)(&ldsB[cur][row * 64 + slot * 8]);
      }
#pragma unroll
      for (int m = 0; m < 4; ++m)
#pragma unroll
        for (int n = 0; n < 4; ++n)
          acc[m][n] = __builtin_amdgcn_mfma_f32_16x16x32_bf16(af[m], bfr[n],
                                                              acc[m][n], 0, 0, 0);
    }
    __builtin_amdgcn_s_setprio(0);

    asm volatile("s_waitcnt vmcnt(0)" ::: "memory");  // next tile landed
    __syncthreads();                                  // all reads of cur done
    cur ^= 1;
  }

  const int row0 = bm + wr * 64 + g * 4;
  const int col0 = bn + wc * 64 + r;
  const int region = bn >> 10;
  const int b = blockIdx.y >> 4;                     // 128 rows/block
  const int sbase = (bm & 2047) + wr * 64 + g * 4;   // s for i=0,m=0

  if (region == 0) {
    // Q: row-major, stride 1024
#pragma unroll
    for (int m = 0; m < 4; ++m)
#pragma unroll
      for (int n = 0; n < 4; ++n)
#pragma unroll
        for (int i = 0; i < 4; ++i)
          qb[(size_t)(row0 + m * 16 + i) * D_ + col0 + n * 16] = f2bf(acc[m][n][i]);
  } else if (region == 1) {
    // K packed: element (c,hi,l,j) = K[32tau+l][16c+8hi+j]
    const int h = ((bn - 1024) >> 6) + wc;
    unsigned short* kpb = kp + (size_t)(b * 16 + h) * 131072;
#pragma unroll
    for (int m = 0; m < 4; ++m) {
      const int s = sbase + m * 16;
      const int tau = s >> 5, l = s & 31;
#pragma unroll
      for (int n = 0; n < 4; ++n) {
        unsigned short* kq = kpb + tau * 2048 +
                             (n * 64 + (r >> 3) * 32 + l) * 8 + (r & 7);
        kq[0]  = f2bf(acc[m][n][0]);
        kq[8]  = f2bf(acc[m][n][1]);
        kq[16] = f2bf(acc[m][n][2]);
        kq[24] = f2bf(acc[m][n][3]);
      }
    }
  } else {
    // V packed: addr = tau2*4096 + (T*256 + c*128 + half*64 + hi*32 + l)*8 + u
    const int h = ((bn - 2048) >> 6) + wc;
    unsigned short* vpb = vp + (size_t)(b * 16 + h) * 131072;
#pragma unroll
    for (int m = 0; m < 4; ++m) {
      const int s = sbase + m * 16;
      const int tau2 = s >> 6;
      const int T = (s >> 5) & 1, c16 = (s >> 4) & 1, hi8 = (s >> 3) & 1;
      const int u = s & 7;                       // in {0,4}
#pragma unroll
      for (int n = 0; n < 4; ++n) {
        const int half = n >> 1;
        const int l = (n & 1) * 16 + r;
        const int tid = T * 256 + c16 * 128 + half * 64 + hi8 * 32 + l;
        unsigned long long pk2 =
            (unsigned long long)pkbf(acc[m][n][0], acc[m][n][1]) |
            ((unsigned long long)pkbf(acc[m][n][2], acc[m][n][3]) << 32);
        *(unsigned long long*)(vpb + tau2 * 4096 + tid * 8 + u) = pk2;
      }
    }
  }
}

// ---------------- GEMM proj: 64x128 tile, 2-PHASE double-buffered --------
__global__ __launch_bounds__(256) void k_gemm_bt64(const unsigned short* __restrict__ A,
                                                   const unsigned short* __restrict__ Bt,
                                                   float* __restrict__ C,
                                                   int Ndim, int K) {
  __shared__ __align__(16) unsigned short ldsA[2][64 * 64];
  __shared__ __align__(16) unsigned short ldsB[2][128 * 64];
  const int t = threadIdx.x;
  const int lane = t & 63;
  const int wid = t >> 6;
  const int wr = wid >> 1, wc = wid & 1;   // wave: 32 rows x 64 cols
  const int bm = blockIdx.y * 64, bn = blockIdx.x * 128;
  const int r = lane & 15, g = lane >> 4;

  f32x4 acc[2][4] = {};

  auto stage = [&](int buf, int kt) {
#pragma unroll
    for (int c = 0; c < 2; ++c) {
      const int idx = c * 256 + t;
      const int row = idx >> 3;
      const int col = ((idx & 7) ^ (row & 7)) * 8;
      gload16(A + (size_t)(bm + row) * K + kt + col, &ldsA[buf][idx * 8]);
    }
#pragma unroll
    for (int c = 0; c < 4; ++c) {
      const int idx = c * 256 + t;
      const int row = idx >> 3;
      const int col = ((idx & 7) ^ (row & 7)) * 8;
      gload16(Bt + (size_t)(bn + row) * K + kt + col, &ldsB[buf][idx * 8]);
    }
  };

  stage(0, 0);
  asm volatile("s_waitcnt vmcnt(0)" ::: "memory");
  __syncthreads();

  int cur = 0;
  for (int kt = 0; kt < K; kt += 64) {
    if (kt + 64 < K) stage(cur ^ 1, kt + 64);

    __builtin_amdgcn_s_setprio(1);
#pragma unroll
    for (int ks = 0; ks < 2; ++ks) {
      bf16x8 af[2], bfr[4];
#pragma unroll
      for (int m = 0; m < 2; ++m) {
        const int row = wr * 32 + m * 16 + r;
        const int slot = (ks * 4 + g) ^ (row & 7);
        af[m] = *(const bf16x8*)(&ldsA[cur][row * 64 + slot * 8]);
      }
#pragma unroll
      for (int n = 0; n < 4; ++n) {
        const int row = wc * 64 + n * 16 + r;
        const int slot = (ks * 4 + g) ^ (row & 7);
        bfr[n] = *(const bf16x8*)(&ldsB[cur][row * 64 + slot * 8]);
      }
#pragma unroll
      for (int m = 0; m < 2; ++m)
#pragma unroll
        for (int n = 0; n < 4; ++n)
          acc[m][n] = __builtin_amdgcn_mfma_f32_16x16x32_bf16(af[m], bfr[n],
                                                              acc[m][n], 0, 0, 0);
    }
    __builtin_amdgcn_s_setprio(0);

    asm volatile("s_waitcnt vmcnt(0)" ::: "memory");
    __syncthreads();
    cur ^= 1;
  }

  const int row0 = bm + wr * 32 + g * 4;
  const int col0 = bn + wc * 64 + r;
#pragma unroll
  for (int m = 0; m < 2; ++m)
#pragma unroll
    for (int n = 0; n < 4; ++n)
#pragma unroll
      for (int i = 0; i < 4; ++i)
        C[(size_t)(row0 + m * 16 + i) * Ndim + col0 + n * 16] = acc[m][n][i];
}

// ---------------- fused causal attention (round-10 proven, 39.9us) -------
__global__ __launch_bounds__(256, 4) void k_attn(const unsigned short* __restrict__ qb,
                                                 const unsigned short* __restrict__ kp,
                                                 const unsigned short* __restrict__ vp,
                                                 unsigned short* __restrict__ y) {
  __shared__ __align__(16) float Om[2][64][32];
  __shared__ float Ml[2][2][32];
  const int t = threadIdx.x;
  const int lane = t & 63, w = t >> 6;
  const int l31 = lane & 31, hi = lane >> 5;
  const int pr = w & 1;                      // slot index within block
  const int parity = w >> 1;                 // KV parity (0,1)
  const int bh = blockIdx.x & 31;
  const int j = blockIdx.x >> 5;             // 0..31
  const int sj = pr ? (63 - j) : j;          // this wave's q-slot 0..63
  const int h = bh & 15, b = bh >> 4;
  const int qbase = 32 * sj;
  const int qq = qbase + l31;

  const float SC = 0.125f * 1.44269504f;     // scale * log2(e) -> exp2 domain

  bf16x8 qf[4];
  {
    const unsigned short* qp = qb + (size_t)(b * S_ + qbase + l31) * D_ + h * HD_;
#pragma unroll
    for (int c = 0; c < 4; ++c) {
      bf16x8 rl = *(const bf16x8*)(qp + c * 16 + hi * 8);
      union { unsigned int u[4]; bf16x8 v; } pl;
#pragma unroll
      for (int jx = 0; jx < 4; ++jx)
        pl.u[jx] = pkbf((float)rl[2 * jx] * SC, (float)rl[2 * jx + 1] * SC);
      qf[c] = pl.v;
    }
  }

  float mr = MINITVAL, lr = 0.f;
  f32x16 o0 = {}, o1 = {};

  const unsigned short* kpb = kp + (size_t)bh * 131072;
  const unsigned short* vpb = vp + (size_t)bh * 131072;

  const int tmax = (32 * sj + 31) >> 6;      // last tile needed for this slot

  for (int kvt = parity; kvt <= tmax; kvt += 2) {
    const int kv0 = kvt << 6;
    bf16x8 kf[2][4];
#pragma unroll
    for (int T = 0; T < 2; ++T)
#pragma unroll
      for (int c = 0; c < 4; ++c)
        kf[T][c] = *(const bf16x8*)(kpb + (size_t)(kvt * 8 + T * 4 + c) * 512 +
                                    lane * 8);

    // ---- QK^T ----
    f32x16 s0 = {}, s1 = {};
    __builtin_amdgcn_s_setprio(1);
#pragma unroll
    for (int c = 0; c < 4; ++c) {
      s0 = __builtin_amdgcn_mfma_f32_32x32x16_bf16(kf[0][c], qf[c], s0, 0, 0, 0);
      s1 = __builtin_amdgcn_mfma_f32_32x32x16_bf16(kf[1][c], qf[c], s1, 0, 0, 0);
    }
    __builtin_amdgcn_s_setprio(0);

    // ---- mask + 4-chain max reduction ----
    float am[4] = {MASKVAL, MASKVAL, MASKVAL, MASKVAL};
    if (kv0 + 63 > qbase) {
#pragma unroll
      for (int rg = 0; rg < 16; ++rg) {
        const int kv = kv0 + (rg & 3) + 8 * (rg >> 2) + 4 * hi;
        float v0 = (kv <= qq) ? s0[rg] : MASKVAL; s0[rg] = v0;
        float v1 = (kv + 32 <= qq) ? s1[rg] : MASKVAL; s1[rg] = v1;
        am[rg & 3] = fmaxf(am[rg & 3], fmaxf(v0, v1));
      }
    } else {
#pragma unroll
      for (int rg = 0; rg < 16; ++rg)
        am[rg & 3] = fmaxf(am[rg & 3], fmaxf(s0[rg], s1[rg]));
    }
    const float pm = xmax32(fmaxf(fmaxf(am[0], am[1]), fmaxf(am[2], am[3])));

    // ---- defer-rescale (log2 domain, THR = 12) ----
    const float nm = fmaxf(mr, pm);
    if (!__all(nm - mr <= 12.0f)) {
      const float cr = exp2a(mr - nm);
      mr = nm;
      lr *= cr;
#pragma unroll
      for (int rg = 0; rg < 16; ++rg) { o0[rg] *= cr; o1[rg] *= cr; }
    }

    // ---- p = exp2(s - m), 4-chain sum ----
    float as[4] = {0.f, 0.f, 0.f, 0.f};
#pragma unroll
    for (int rg = 0; rg < 16; ++rg) {
      const float p0 = exp2a(s0[rg] - mr); s0[rg] = p0;
      const float p1 = exp2a(s1[rg] - mr); s1[rg] = p1;
      as[rg & 3] += p0 + p1;
    }
    lr += xadd32((as[0] + as[1]) + (as[2] + as[3]));

    // ---- P^T in-register, O^T += V^T P^T ----
    const unsigned short* vpt = vpb + (size_t)kvt * 4096;
    __builtin_amdgcn_s_setprio(1);
#pragma unroll
    for (int T = 0; T < 2; ++T) {
      const f32x16& sT = T ? s1 : s0;
#pragma unroll
      for (int c = 0; c < 2; ++c) {
        unsigned int x0 = pkbf(sT[8 * c + 0], sT[8 * c + 1]);
        unsigned int x1 = pkbf(sT[8 * c + 2], sT[8 * c + 3]);
        unsigned int x2 = pkbf(sT[8 * c + 4], sT[8 * c + 5]);
        unsigned int x3 = pkbf(sT[8 * c + 6], sT[8 * c + 7]);
        plswap(x0, x2);
        plswap(x1, x3);
        union { unsigned int u[4]; bf16x8 v; } pb;
        pb.u[0] = x0; pb.u[1] = x1; pb.u[2] = x2; pb.u[3] = x3;
        const unsigned short* vb = vpt + (size_t)((T * 2 + c) * 2) * 512 + lane * 8;
        bf16x8 vf0 = *(const bf16x8*)(vb);
        bf16x8 vf1 = *(const bf16x8*)(vb + 512);
        o0 = __builtin_amdgcn_mfma_f32_32x32x16_bf16(vf0, pb.v, o0, 0, 0, 0);
        o1 = __builtin_amdgcn_mfma_f32_32x32x16_bf16(vf1, pb.v, o1, 0, 0, 0);
      }
    }
    __builtin_amdgcn_s_setprio(0);
  }

  // ---- parity merge (proven 2-barrier structure) + store ----
  __syncthreads();
  if (parity) {   // w2, w3 publish
#pragma unroll
    for (int tt = 0; tt < 2; ++tt) {
      const f32x16& o = tt ? o1 : o0;
#pragma unroll
      for (int rg = 0; rg < 16; ++rg) {
        const int row = tt * 32 + (rg & 3) + 8 * (rg >> 2) + 4 * hi;
        Om[pr][row][l31] = o[rg];
      }
    }
    if (!hi) {
      Ml[pr][0][l31] = mr;
      Ml[pr][1][l31] = lr;
    }
  }
  __syncthreads();
  if (!parity) {  // w0, w1 merge + store
    const float mo = Ml[pr][0][l31];
    const float lo2 = Ml[pr][1][l31];
    const float mm = fmaxf(mr, mo);
    const float ce = exp2a(mr - mm), co = exp2a(mo - mm);
    const float lt = lr * ce + lo2 * co;
    const float ic = ce / lt, io = co / lt;
    unsigned short* yp = y + (size_t)(b * S_ + qbase + l31) * D_ + h * HD_;
#pragma unroll
    for (int tt = 0; tt < 2; ++tt) {
      const f32x16& o = tt ? o1 : o0;
#pragma unroll
      for (int rg = 0; rg < 16; rg += 2) {
        const int row = tt * 32 + (rg & 3) + 8 * (rg >> 2) + 4 * hi;
        const float v0 = o[rg] * ic + Om[pr][row][l31] * io;
        const float v1 = o[rg + 1] * ic + Om[pr][row + 1][l31] * io;
        *(unsigned int*)(yp + row) = pkbf(v0, v1);
      }
    }
  }
}

// ---------------- launch ----------------
extern "C" void kernel_launch(void* const* d_in, const int* in_sizes, int n_in,
                              void* d_out, int out_size, void* d_ws, size_t ws_size,
                              hipStream_t stream) {
  const float* x  = (const float*)d_in[0];   // [2,2048,1024]
  const float* wa = (const float*)d_in[1];   // [1024,3072]
  const float* wp = (const float*)d_in[2];   // [1024,1024]
  float* out = (float*)d_out;                // [2,2048,1024] fp32

  char* ws = (char*)d_ws;
  unsigned short* xb  = (unsigned short*)(ws + 0);          //  8 MiB: x bf16
  unsigned short* waT = (unsigned short*)(ws + 8388608);    //  6 MiB: w_attn^T
  unsigned short* wpT = (unsigned short*)(ws + 14680064);   //  2 MiB: w_proj^T
  unsigned short* qb  = (unsigned short*)(ws + 16777216);   //  8 MiB: Q [4096][1024]
  unsigned short* kp  = (unsigned short*)(ws + 25165824);   //  8 MiB: packed K
  unsigned short* vp  = (unsigned short*)(ws + 33554432);   //  8 MiB: packed V
  unsigned short* yb  = (unsigned short*)(ws + 41943040);   //  8 MiB: attn out

  k_prep<<<5120, 256, 0, stream>>>(x, wa, wp, xb, waT, wpT);
  k_gemm_qkv<<<dim3(24, 32), 256, 0, stream>>>(xb, waT, qb, kp, vp);
  k_attn<<<1024, 256, 0, stream>>>(qb, kp, vp, yb);
  k_gemm_bt64<<<dim3(8, 64), 256, 0, stream>>>(yb, wpT, out, D_, D_);
}

// Round 23
// 105.099 us; speedup vs baseline: 1.0492x; 1.0492x over previous
//
#include <hip/hip_runtime.h>

// Problem constants: B=2, S=2048, D=1024, H=16, HD=64
#define B_  2
#define S_  2048
#define D_  1024
#define H_  16
#define HD_ 64
#define TD_ 3072   // 3*D

typedef __bf16 bf16x8 __attribute__((ext_vector_type(8)));
typedef float  f32x4  __attribute__((ext_vector_type(4)));
typedef float  f32x16 __attribute__((ext_vector_type(16)));

#define AS1 __attribute__((address_space(1)))
#define AS3 __attribute__((address_space(3)))

#define MASKVAL (-60000.0f)
#define MINITVAL (-30000.0f)

__device__ __forceinline__ unsigned short f2bf(float f) {
  return __builtin_bit_cast(unsigned short, (__bf16)f);
}

__device__ __forceinline__ unsigned int pkbf(float lo, float hi) {
  unsigned int r;
  asm("v_cvt_pk_bf16_f32 %0, %1, %2" : "=v"(r) : "v"(lo), "v"(hi));
  return r;
}

// v_permlane32_swap_b32: a[32+i] <-> b[i]  (proven, distinct operands)
__device__ __forceinline__ void plswap(unsigned int& a, unsigned int& b) {
  asm volatile("v_permlane32_swap_b32 %0, %1" : "+v"(a), "+v"(b));
}

__device__ __forceinline__ float exp2a(float x) {
  return __builtin_amdgcn_exp2f(x);
}

__device__ __forceinline__ float xmax32(float x) {
  return fmaxf(x, __shfl_xor(x, 32, 64));
}
__device__ __forceinline__ float xadd32(float x) {
  return x + __shfl_xor(x, 32, 64);
}

__device__ __forceinline__ void gload16(const void* g, void* l) {
  __builtin_amdgcn_global_load_lds((const AS1 void*)g, (AS3 void*)l, 16, 0, 0);
}

// ---------------- fused prep: x->bf16  AND  both W transposes ------------
__global__ __launch_bounds__(256) void k_prep(const float* __restrict__ x,
                                              const float* __restrict__ wa,
                                              const float* __restrict__ wp,
                                              unsigned short* __restrict__ xb,
                                              unsigned short* __restrict__ waT,
                                              unsigned short* __restrict__ wpT) {
  __shared__ __align__(16) unsigned short tile[64][72];
  const int t = threadIdx.x;
  const int bid = blockIdx.x;
  if (bid < 4096) {
    const int i = (bid * 256 + t) * 4;
    float4 v = *(const float4*)(x + i);
    ushort4 o;
    o.x = f2bf(v.x); o.y = f2bf(v.y); o.z = f2bf(v.z); o.w = f2bf(v.w);
    *(ushort4*)(xb + i) = o;
    return;
  }
  const int idx = bid - 4096;               // 0..1023
  const int bx = idx & 63;                  // 0..63
  const int by = idx >> 6;                  // 0..15
  const float* w;
  unsigned short* wt;
  int C, c0;
  if (bx < 48) { w = wa; wt = waT; C = TD_; c0 = bx * 64; }
  else         { w = wp; wt = wpT; C = D_;  c0 = (bx - 48) * 64; }
  const int R = D_;
  const int r0 = by * 64;
  const int rr = t >> 2, cc = (t & 3) * 16;
  const float* src = w + (size_t)(r0 + rr) * C + c0 + cc;
#pragma unroll
  for (int j = 0; j < 16; j += 4) {
    float4 v = *(const float4*)(src + j);
    tile[rr][cc + j + 0] = f2bf(v.x);
    tile[rr][cc + j + 1] = f2bf(v.y);
    tile[rr][cc + j + 2] = f2bf(v.z);
    tile[rr][cc + j + 3] = f2bf(v.w);
  }
  __syncthreads();
  unsigned short* dst = wt + (size_t)(c0 + rr) * R + r0 + cc;
#pragma unroll
  for (int j = 0; j < 16; j += 2) {
    unsigned int pk = (unsigned int)tile[cc + j][rr] |
                      ((unsigned int)tile[cc + j + 1][rr] << 16);
    *(unsigned int*)(dst + j) = pk;
  }
}

// ---------------- GEMM qkv: 64x128 tile, 2-PHASE double-buffered ---------
// (round-20/21 proven winner) stage(t+1) BEFORE compute(t); one
// vmcnt(0)+barrier per K-step. Fused epilogue: Q row-major, K/V packed.
__global__ __launch_bounds__(256) void k_gemm_qkv(const unsigned short* __restrict__ A,
                                                  const unsigned short* __restrict__ Bt,
                                                  unsigned short* __restrict__ qb,
                                                  unsigned short* __restrict__ kp,
                                                  unsigned short* __restrict__ vp) {
  __shared__ __align__(16) unsigned short ldsA[2][64 * 64];
  __shared__ __align__(16) unsigned short ldsB[2][128 * 64];
  const int K = D_;
  const int t = threadIdx.x;
  const int lane = t & 63;
  const int wid = t >> 6;
  const int wr = wid >> 1, wc = wid & 1;   // wave: 32 rows x 64 cols
  const int bx = blockIdx.x;
  const int bm = blockIdx.y * 64;
  const int bn = (((bx & 7) * 3) + (bx >> 3)) * 128;   // bijective for 24
  const int r = lane & 15, g = lane >> 4;

  f32x4 acc[2][4] = {};

  auto stage = [&](int buf, int kt) {
#pragma unroll
    for (int c = 0; c < 2; ++c) {
      const int idx = c * 256 + t;
      const int row = idx >> 3;
      const int col = ((idx & 7) ^ (row & 7)) * 8;
      gload16(A + (size_t)(bm + row) * K + kt + col, &ldsA[buf][idx * 8]);
    }
#pragma unroll
    for (int c = 0; c < 4; ++c) {
      const int idx = c * 256 + t;
      const int row = idx >> 3;
      const int col = ((idx & 7) ^ (row & 7)) * 8;
      gload16(Bt + (size_t)(bn + row) * K + kt + col, &ldsB[buf][idx * 8]);
    }
  };

  stage(0, 0);
  asm volatile("s_waitcnt vmcnt(0)" ::: "memory");
  __syncthreads();

  int cur = 0;
  for (int kt = 0; kt < K; kt += 64) {
    if (kt + 64 < K) stage(cur ^ 1, kt + 64);   // issue next tile's loads

    __builtin_amdgcn_s_setprio(1);
#pragma unroll
    for (int ks = 0; ks < 2; ++ks) {
      bf16x8 af[2], bfr[4];
#pragma unroll
      for (int m = 0; m < 2; ++m) {
        const int row = wr * 32 + m * 16 + r;
        const int slot = (ks * 4 + g) ^ (row & 7);
        af[m] = *(const bf16x8*)(&ldsA[cur][row * 64 + slot * 8]);
      }
#pragma unroll
      for (int n = 0; n < 4; ++n) {
        const int row = wc * 64 + n * 16 + r;
        const int slot = (ks * 4 + g) ^ (row & 7);
        bfr[n] = *(const bf16x8*)(&ldsB[cur][row * 64 + slot * 8]);
      }
#pragma unroll
      for (int m = 0; m < 2; ++m)
#pragma unroll
        for (int n = 0; n < 4; ++n)
          acc[m][n] = __builtin_amdgcn_mfma_f32_16x16x32_bf16(af[m], bfr[n],
                                                              acc[m][n], 0, 0, 0);
    }
    __builtin_amdgcn_s_setprio(0);

    asm volatile("s_waitcnt vmcnt(0)" ::: "memory");  // next tile landed
    __syncthreads();                                  // all reads of cur done
    cur ^= 1;
  }

  const int row0 = bm + wr * 32 + g * 4;
  const int col0 = bn + wc * 64 + r;
  const int region = bn >> 10;
  const int b = blockIdx.y >> 5;                     // 64 rows/block
  const int sbase = (bm & 2047) + wr * 32 + g * 4;   // s for i=0,m=0

  if (region == 0) {
#pragma unroll
    for (int m = 0; m < 2; ++m)
#pragma unroll
      for (int n = 0; n < 4; ++n)
#pragma unroll
        for (int i = 0; i < 4; ++i)
          qb[(size_t)(row0 + m * 16 + i) * D_ + col0 + n * 16] = f2bf(acc[m][n][i]);
  } else if (region == 1) {
    const int h = ((bn - 1024) >> 6) + wc;
    unsigned short* kpb = kp + (size_t)(b * 16 + h) * 131072;
#pragma unroll
    for (int m = 0; m < 2; ++m) {
      const int s = sbase + m * 16;
      const int tau = s >> 5, l = s & 31;
#pragma unroll
      for (int n = 0; n < 4; ++n) {
        unsigned short* kq = kpb + tau * 2048 +
                             (n * 64 + (r >> 3) * 32 + l) * 8 + (r & 7);
        kq[0]  = f2bf(acc[m][n][0]);
        kq[8]  = f2bf(acc[m][n][1]);
        kq[16] = f2bf(acc[m][n][2]);
        kq[24] = f2bf(acc[m][n][3]);
      }
    }
  } else {
    const int h = ((bn - 2048) >> 6) + wc;
    unsigned short* vpb = vp + (size_t)(b * 16 + h) * 131072;
#pragma unroll
    for (int m = 0; m < 2; ++m) {
      const int s = sbase + m * 16;
      const int tau2 = s >> 6;
      const int T = (s >> 5) & 1, c16 = (s >> 4) & 1, hi8 = (s >> 3) & 1;
      const int u = s & 7;                       // in {0,4}
#pragma unroll
      for (int n = 0; n < 4; ++n) {
        const int half = n >> 1;
        const int l = (n & 1) * 16 + r;
        const int tid = T * 256 + c16 * 128 + half * 64 + hi8 * 32 + l;
        unsigned long long pk2 =
            (unsigned long long)pkbf(acc[m][n][0], acc[m][n][1]) |
            ((unsigned long long)pkbf(acc[m][n][2], acc[m][n][3]) << 32);
        *(unsigned long long*)(vpb + tau2 * 4096 + tid * 8 + u) = pk2;
      }
    }
  }
}

// ---------------- GEMM proj: 64x128 tile, 2-PHASE double-buffered --------
__global__ __launch_bounds__(256) void k_gemm_bt64(const unsigned short* __restrict__ A,
                                                   const unsigned short* __restrict__ Bt,
                                                   float* __restrict__ C,
                                                   int Ndim, int K) {
  __shared__ __align__(16) unsigned short ldsA[2][64 * 64];
  __shared__ __align__(16) unsigned short ldsB[2][128 * 64];
  const int t = threadIdx.x;
  const int lane = t & 63;
  const int wid = t >> 6;
  const int wr = wid >> 1, wc = wid & 1;   // wave: 32 rows x 64 cols
  const int bm = blockIdx.y * 64, bn = blockIdx.x * 128;
  const int r = lane & 15, g = lane >> 4;

  f32x4 acc[2][4] = {};

  auto stage = [&](int buf, int kt) {
#pragma unroll
    for (int c = 0; c < 2; ++c) {
      const int idx = c * 256 + t;
      const int row = idx >> 3;
      const int col = ((idx & 7) ^ (row & 7)) * 8;
      gload16(A + (size_t)(bm + row) * K + kt + col, &ldsA[buf][idx * 8]);
    }
#pragma unroll
    for (int c = 0; c < 4; ++c) {
      const int idx = c * 256 + t;
      const int row = idx >> 3;
      const int col = ((idx & 7) ^ (row & 7)) * 8;
      gload16(Bt + (size_t)(bn + row) * K + kt + col, &ldsB[buf][idx * 8]);
    }
  };

  stage(0, 0);
  asm volatile("s_waitcnt vmcnt(0)" ::: "memory");
  __syncthreads();

  int cur = 0;
  for (int kt = 0; kt < K; kt += 64) {
    if (kt + 64 < K) stage(cur ^ 1, kt + 64);

    __builtin_amdgcn_s_setprio(1);
#pragma unroll
    for (int ks = 0; ks < 2; ++ks) {
      bf16x8 af[2], bfr[4];
#pragma unroll
      for (int m = 0; m < 2; ++m) {
        const int row = wr * 32 + m * 16 + r;
        const int slot = (ks * 4 + g) ^ (row & 7);
        af[m] = *(const bf16x8*)(&ldsA[cur][row * 64 + slot * 8]);
      }
#pragma unroll
      for (int n = 0; n < 4; ++n) {
        const int row = wc * 64 + n * 16 + r;
        const int slot = (ks * 4 + g) ^ (row & 7);
        bfr[n] = *(const bf16x8*)(&ldsB[cur][row * 64 + slot * 8]);
      }
#pragma unroll
      for (int m = 0; m < 2; ++m)
#pragma unroll
        for (int n = 0; n < 4; ++n)
          acc[m][n] = __builtin_amdgcn_mfma_f32_16x16x32_bf16(af[m], bfr[n],
                                                              acc[m][n], 0, 0, 0);
    }
    __builtin_amdgcn_s_setprio(0);

    asm volatile("s_waitcnt vmcnt(0)" ::: "memory");
    __syncthreads();
    cur ^= 1;
  }

  const int row0 = bm + wr * 32 + g * 4;
  const int col0 = bn + wc * 64 + r;
#pragma unroll
  for (int m = 0; m < 2; ++m)
#pragma unroll
    for (int n = 0; n < 4; ++n)
#pragma unroll
      for (int i = 0; i < 4; ++i)
        C[(size_t)(row0 + m * 16 + i) * Ndim + col0 + n * 16] = acc[m][n][i];
}

// ---------------- fused causal attention (round-10 proven, 39.9us) -------
__global__ __launch_bounds__(256, 4) void k_attn(const unsigned short* __restrict__ qb,
                                                 const unsigned short* __restrict__ kp,
                                                 const unsigned short* __restrict__ vp,
                                                 unsigned short* __restrict__ y) {
  __shared__ __align__(16) float Om[2][64][32];
  __shared__ float Ml[2][2][32];
  const int t = threadIdx.x;
  const int lane = t & 63, w = t >> 6;
  const int l31 = lane & 31, hi = lane >> 5;
  const int pr = w & 1;                      // slot index within block
  const int parity = w >> 1;                 // KV parity (0,1)
  const int bh = blockIdx.x & 31;
  const int j = blockIdx.x >> 5;             // 0..31
  const int sj = pr ? (63 - j) : j;          // this wave's q-slot 0..63
  const int h = bh & 15, b = bh >> 4;
  const int qbase = 32 * sj;
  const int qq = qbase + l31;

  const float SC = 0.125f * 1.44269504f;     // scale * log2(e) -> exp2 domain

  bf16x8 qf[4];
  {
    const unsigned short* qp = qb + (size_t)(b * S_ + qbase + l31) * D_ + h * HD_;
#pragma unroll
    for (int c = 0; c < 4; ++c) {
      bf16x8 rl = *(const bf16x8*)(qp + c * 16 + hi * 8);
      union { unsigned int u[4]; bf16x8 v; } pl;
#pragma unroll
      for (int jx = 0; jx < 4; ++jx)
        pl.u[jx] = pkbf((float)rl[2 * jx] * SC, (float)rl[2 * jx + 1] * SC);
      qf[c] = pl.v;
    }
  }

  float mr = MINITVAL, lr = 0.f;
  f32x16 o0 = {}, o1 = {};

  const unsigned short* kpb = kp + (size_t)bh * 131072;
  const unsigned short* vpb = vp + (size_t)bh * 131072;

  const int tmax = (32 * sj + 31) >> 6;      // last tile needed for this slot

  for (int kvt = parity; kvt <= tmax; kvt += 2) {
    const int kv0 = kvt << 6;
    bf16x8 kf[2][4];
#pragma unroll
    for (int T = 0; T < 2; ++T)
#pragma unroll
      for (int c = 0; c < 4; ++c)
        kf[T][c] = *(const bf16x8*)(kpb + (size_t)(kvt * 8 + T * 4 + c) * 512 +
                                    lane * 8);

    // ---- QK^T ----
    f32x16 s0 = {}, s1 = {};
    __builtin_amdgcn_s_setprio(1);
#pragma unroll
    for (int c = 0; c < 4; ++c) {
      s0 = __builtin_amdgcn_mfma_f32_32x32x16_bf16(kf[0][c], qf[c], s0, 0, 0, 0);
      s1 = __builtin_amdgcn_mfma_f32_32x32x16_bf16(kf[1][c], qf[c], s1, 0, 0, 0);
    }
    __builtin_amdgcn_s_setprio(0);

    // ---- mask + 4-chain max reduction ----
    float am[4] = {MASKVAL, MASKVAL, MASKVAL, MASKVAL};
    if (kv0 + 63 > qbase) {
#pragma unroll
      for (int rg = 0; rg < 16; ++rg) {
        const int kv = kv0 + (rg & 3) + 8 * (rg >> 2) + 4 * hi;
        float v0 = (kv <= qq) ? s0[rg] : MASKVAL; s0[rg] = v0;
        float v1 = (kv + 32 <= qq) ? s1[rg] : MASKVAL; s1[rg] = v1;
        am[rg & 3] = fmaxf(am[rg & 3], fmaxf(v0, v1));
      }
    } else {
#pragma unroll
      for (int rg = 0; rg < 16; ++rg)
        am[rg & 3] = fmaxf(am[rg & 3], fmaxf(s0[rg], s1[rg]));
    }
    const float pm = xmax32(fmaxf(fmaxf(am[0], am[1]), fmaxf(am[2], am[3])));

    // ---- defer-rescale (log2 domain, THR = 12) ----
    const float nm = fmaxf(mr, pm);
    if (!__all(nm - mr <= 12.0f)) {
      const float cr = exp2a(mr - nm);
      mr = nm;
      lr *= cr;
#pragma unroll
      for (int rg = 0; rg < 16; ++rg) { o0[rg] *= cr; o1[rg] *= cr; }
    }

    // ---- p = exp2(s - m), 4-chain sum ----
    float as[4] = {0.f, 0.f, 0.f, 0.f};
#pragma unroll
    for (int rg = 0; rg < 16; ++rg) {
      const float p0 = exp2a(s0[rg] - mr); s0[rg] = p0;
      const float p1 = exp2a(s1[rg] - mr); s1[rg] = p1;
      as[rg & 3] += p0 + p1;
    }
    lr += xadd32((as[0] + as[1]) + (as[2] + as[3]));

    // ---- P^T in-register, O^T += V^T P^T ----
    const unsigned short* vpt = vpb + (size_t)kvt * 4096;
    __builtin_amdgcn_s_setprio(1);
#pragma unroll
    for (int T = 0; T < 2; ++T) {
      const f32x16& sT = T ? s1 : s0;
#pragma unroll
      for (int c = 0; c < 2; ++c) {
        unsigned int x0 = pkbf(sT[8 * c + 0], sT[8 * c + 1]);
        unsigned int x1 = pkbf(sT[8 * c + 2], sT[8 * c + 3]);
        unsigned int x2 = pkbf(sT[8 * c + 4], sT[8 * c + 5]);
        unsigned int x3 = pkbf(sT[8 * c + 6], sT[8 * c + 7]);
        plswap(x0, x2);
        plswap(x1, x3);
        union { unsigned int u[4]; bf16x8 v; } pb;
        pb.u[0] = x0; pb.u[1] = x1; pb.u[2] = x2; pb.u[3] = x3;
        const unsigned short* vb = vpt + (size_t)((T * 2 + c) * 2) * 512 + lane * 8;
        bf16x8 vf0 = *(const bf16x8*)(vb);
        bf16x8 vf1 = *(const bf16x8*)(vb + 512);
        o0 = __builtin_amdgcn_mfma_f32_32x32x16_bf16(vf0, pb.v, o0, 0, 0, 0);
        o1 = __builtin_amdgcn_mfma_f32_32x32x16_bf16(vf1, pb.v, o1, 0, 0, 0);
      }
    }
    __builtin_amdgcn_s_setprio(0);
  }

  // ---- parity merge (proven 2-barrier structure) + store ----
  __syncthreads();
  if (parity) {   // w2, w3 publish
#pragma unroll
    for (int tt = 0; tt < 2; ++tt) {
      const f32x16& o = tt ? o1 : o0;
#pragma unroll
      for (int rg = 0; rg < 16; ++rg) {
        const int row = tt * 32 + (rg & 3) + 8 * (rg >> 2) + 4 * hi;
        Om[pr][row][l31] = o[rg];
      }
    }
    if (!hi) {
      Ml[pr][0][l31] = mr;
      Ml[pr][1][l31] = lr;
    }
  }
  __syncthreads();
  if (!parity) {  // w0, w1 merge + store
    const float mo = Ml[pr][0][l31];
    const float lo2 = Ml[pr][1][l31];
    const float mm = fmaxf(mr, mo);
    const float ce = exp2a(mr - mm), co = exp2a(mo - mm);
    const float lt = lr * ce + lo2 * co;
    const float ic = ce / lt, io = co / lt;
    unsigned short* yp = y + (size_t)(b * S_ + qbase + l31) * D_ + h * HD_;
#pragma unroll
    for (int tt = 0; tt < 2; ++tt) {
      const f32x16& o = tt ? o1 : o0;
#pragma unroll
      for (int rg = 0; rg < 16; rg += 2) {
        const int row = tt * 32 + (rg & 3) + 8 * (rg >> 2) + 4 * hi;
        const float v0 = o[rg] * ic + Om[pr][row][l31] * io;
        const float v1 = o[rg + 1] * ic + Om[pr][row + 1][l31] * io;
        *(unsigned int*)(yp + row) = pkbf(v0, v1);
      }
    }
  }
}

// ---------------- launch ----------------
extern "C" void kernel_launch(void* const* d_in, const int* in_sizes, int n_in,
                              void* d_out, int out_size, void* d_ws, size_t ws_size,
                              hipStream_t stream) {
  const float* x  = (const float*)d_in[0];   // [2,2048,1024]
  const float* wa = (const float*)d_in[1];   // [1024,3072]
  const float* wp = (const float*)d_in[2];   // [1024,1024]
  float* out = (float*)d_out;                // [2,2048,1024] fp32

  char* ws = (char*)d_ws;
  unsigned short* xb  = (unsigned short*)(ws + 0);          //  8 MiB: x bf16
  unsigned short* waT = (unsigned short*)(ws + 8388608);    //  6 MiB: w_attn^T
  unsigned short* wpT = (unsigned short*)(ws + 14680064);   //  2 MiB: w_proj^T
  unsigned short* qb  = (unsigned short*)(ws + 16777216);   //  8 MiB: Q [4096][1024]
  unsigned short* kp  = (unsigned short*)(ws + 25165824);   //  8 MiB: packed K
  unsigned short* vp  = (unsigned short*)(ws + 33554432);   //  8 MiB: packed V
  unsigned short* yb  = (unsigned short*)(ws + 41943040);   //  8 MiB: attn out

  k_prep<<<5120, 256, 0, stream>>>(x, wa, wp, xb, waT, wpT);
  k_gemm_qkv<<<dim3(24, 64), 256, 0, stream>>>(xb, waT, qb, kp, vp);
  k_attn<<<1024, 256, 0, stream>>>(qb, kp, vp, yb);
  k_gemm_bt64<<<dim3(8, 64), 256, 0, stream>>>(yb, wpT, out, D_, D_);
}